// Round 3
// baseline (55177.057 us; speedup 1.0000x reference)
//
#include <hip/hip_runtime.h>

// Reference chain is (hypothesized) numpy float64 mirror of the jnp code.
// Distances/min/argmax computed in f64; no contraction anywhere.
#pragma clang fp contract(off)

#define BATCH  16
#define NPT    32768
#define NPOINT 2048
#define TPB    1024
#define KCH    8          // float4 chunks per thread
#define PPT    32         // points per thread = 4*KCH
#define NWAVES (TPB/64)

// One block per batch. Thread t owns points p = 4*t + 4096*k + j (k<8, j<4).
// x,y fp32 in registers; z fp32 in LDS; dist f64 streamed via global scratch
// (L2-resident, 256KB/batch). Distance chain is float64 end-to-end.
__global__ __launch_bounds__(TPB, 4) void fps_kernel(
    const float* __restrict__ xyz,     // [B, N, 3]
    const int*   __restrict__ init_far,// [B]
    int*         __restrict__ fps_out, // [B, NPOINT]
    double*      __restrict__ distw)   // [B, NPT] f64 scratch
{
#pragma clang fp contract(off)
    __shared__ float  z_lds[NPT];      // 128 KiB
    __shared__ double red_v[NWAVES];
    __shared__ int    red_i[NWAVES];

    const int b = blockIdx.x;
    const int t = threadIdx.x;
    const float* xb = xyz + (size_t)b * NPT * 3;
    double* dw = distw + (size_t)b * NPT;

    float rx[PPT], ry[PPT];

    // ---- init: load owned points (3x float4 = 4 points), z -> LDS, dist -> 1e10
    #pragma unroll
    for (int k = 0; k < KCH; ++k) {
        const int p0 = 4 * t + 4096 * k;
        const float4* v = (const float4*)(xb + (size_t)p0 * 3);
        float4 f0 = v[0], f1 = v[1], f2 = v[2];
        rx[4*k+0] = f0.x; ry[4*k+0] = f0.y;   // p0:   x,y (z=f0.z)
        rx[4*k+1] = f0.w; ry[4*k+1] = f1.x;   // p0+1: x,y (z=f1.y)
        rx[4*k+2] = f1.z; ry[4*k+2] = f1.w;   // p0+2: x,y (z=f2.x)
        rx[4*k+3] = f2.y; ry[4*k+3] = f2.z;   // p0+3: x,y (z=f2.w)
        *(float4*)(&z_lds[p0]) = make_float4(f0.z, f1.y, f2.x, f2.w);
        // 1e10 is exactly representable in fp32 and f64 -> same value either way
        dw[p0+0] = 1e10; dw[p0+1] = 1e10; dw[p0+2] = 1e10; dw[p0+3] = 1e10;
    }

    const int far0 = init_far[b];
    double cx = (double)xb[far0 * 3 + 0];
    double cy = (double)xb[far0 * 3 + 1];
    double cz = (double)xb[far0 * 3 + 2];
    if (t == 0) fps_out[b * NPOINT] = far0;
    __syncthreads();

    const int wave = t >> 6, lane = t & 63;

    for (int it = 0; it < NPOINT; ++it) {
        double best = -1.0;
        int    bestIdx = 0x7fffffff;
        #pragma unroll
        for (int k = 0; k < KCH; ++k) {
            const int p0 = 4 * t + 4096 * k;
            float4 zq = *(const float4*)(&z_lds[p0]);
            double od[4];
            od[0] = dw[p0+0]; od[1] = dw[p0+1]; od[2] = dw[p0+2]; od[3] = dw[p0+3];
            #pragma unroll
            for (int j = 0; j < 4; ++j) {
                float zz = (j == 0) ? zq.x : (j == 1) ? zq.y : (j == 2) ? zq.z : zq.w;
                // f64 mirror of np: dx = x64 - cx64 ; d2 = (dx*dx + dy*dy) + dz*dz
                double dx = (double)rx[4*k+j] - cx;
                double dy = (double)ry[4*k+j] - cy;
                double dz = (double)zz - cz;
                double d2 = (dx*dx + dy*dy) + dz*dz;
                bool upd = d2 < od[j];
                double nd = upd ? d2 : od[j];
                if (upd) dw[p0+j] = nd;       // write-back only on change
                int pidx = p0 + j;
                // ascending pidx per thread -> strict > keeps first occurrence
                bool took = nd > best;
                best    = took ? nd   : best;
                bestIdx = took ? pidx : bestIdx;
            }
        }
        // wave-level argmax, first-index tie-break (lexicographic, associative)
        #pragma unroll
        for (int off = 32; off >= 1; off >>= 1) {
            double ov = __shfl_xor(best, off);
            int    oi = __shfl_xor(bestIdx, off);
            if (ov > best || (ov == best && oi < bestIdx)) { best = ov; bestIdx = oi; }
        }
        if (lane == 0) { red_v[wave] = best; red_i[wave] = bestIdx; }
        __syncthreads();
        double wv = red_v[0];
        int    wi = red_i[0];
        #pragma unroll
        for (int w = 1; w < NWAVES; ++w) {
            double v2 = red_v[w];
            int    i2 = red_i[w];
            if (v2 > wv || (v2 == wv && i2 < wi)) { wv = v2; wi = i2; }
        }
        __syncthreads();   // red_* reads done before next iteration's writes
        if (t == 0 && it + 1 < NPOINT) fps_out[b * NPOINT + it + 1] = wi;
        // broadcast load of next centroid (uniform address, L2-hot)
        cx = (double)xb[wi * 3 + 0];
        cy = (double)xb[wi * 3 + 1];
        cz = (double)xb[wi * 3 + 2];
    }
}

// Gather + transpose: out = [new_xyz (B,3,S) | new_features (B,C,S)], S=2048, C=128
__global__ void gather_kernel(const float* __restrict__ xyz,
                              const float* __restrict__ feat,
                              const int*   __restrict__ fps_idx,
                              float*       __restrict__ out)
{
    const int blk = blockIdx.x;
    const int s = blk & (NPOINT - 1);
    const int b = blk >> 11;
    const int idx = fps_idx[b * NPOINT + s];
    const int c = threadIdx.x;  // 128 threads
    const float v = feat[((size_t)(b * NPT + idx)) * 128 + c];
    out[(size_t)BATCH * 3 * NPOINT + ((size_t)(b * 128 + c)) * NPOINT + s] = v;
    if (c < 3) {
        out[((size_t)(b * 3 + c)) * NPOINT + s] =
            xyz[((size_t)(b * NPT + idx)) * 3 + c];
    }
}

extern "C" void kernel_launch(void* const* d_in, const int* in_sizes, int n_in,
                              void* d_out, int out_size, void* d_ws, size_t ws_size,
                              hipStream_t stream) {
    const float* xyz      = (const float*)d_in[0];  // [16, 32768, 3]
    const float* features = (const float*)d_in[1];  // [16, 32768, 128]
    const int*   init_far = (const int*)d_in[2];    // [16]
    float* out = (float*)d_out;
    int*   fps_idx = (int*)d_ws;                    // 128 KiB in workspace

    // d_out (16.4 MB) doubles as f64 dist scratch (4 MB) during FPS;
    // gather_kernel runs strictly after and overwrites all of d_out.
    double* distw = (double*)d_out;

    fps_kernel<<<BATCH, TPB, 0, stream>>>(xyz, init_far, fps_idx, distw);
    gather_kernel<<<BATCH * NPOINT, 128, 0, stream>>>(xyz, features, fps_idx, out);
}

// Round 4
// 39430.881 us; speedup vs baseline: 1.3993x; 1.3993x over previous
//
#include <hip/hip_runtime.h>

// Reference chain is numpy float64 (verified round 3: absmax == 0).
// Distances/min/argmax computed in f64; no contraction anywhere.
#pragma clang fp contract(off)

#define BATCH  16
#define NPT    32768
#define NPOINT 2048
#define TPB    1024
#define KCH    8          // 4-point chunks per thread
#define PPT    32         // points per thread = 4*KCH
#define NWAVES (TPB/64)

// One block per batch. Thread t owns points p = 4*t + 4096*k + j (k<8, j<4).
// dist f64 lives in REGISTERS (64 VGPR). Coordinates are re-streamed from
// global every iteration (384 KB/batch, L2-resident) as coalesced float4s —
// this removes the round-3 register spill (VGPR=64 + scratch) and the
// 235 MB of f64 dist write-backs.
__global__ __launch_bounds__(TPB, 4) void fps_kernel(
    const float* __restrict__ xyz,     // [B, N, 3]
    const int*   __restrict__ init_far,// [B]
    int*         __restrict__ fps_out) // [B, NPOINT]
{
#pragma clang fp contract(off)
    __shared__ double red_v[2][NWAVES];
    __shared__ int    red_i[2][NWAVES];

    const int b = blockIdx.x;
    const int t = threadIdx.x;
    const float* xb = xyz + (size_t)b * NPT * 3;

    double dist[PPT];
    #pragma unroll
    for (int i = 0; i < PPT; ++i) dist[i] = 1e10;   // f64 1e10, matches np mirror

    const int far0 = init_far[b];
    double cx = (double)xb[far0 * 3 + 0];
    double cy = (double)xb[far0 * 3 + 1];
    double cz = (double)xb[far0 * 3 + 2];
    if (t == 0) fps_out[b * NPOINT] = far0;

    const int wave = t >> 6, lane = t & 63;

    for (int it = 0; it < NPOINT; ++it) {
        double best = -1.0;
        int    bestIdx = 0x7fffffff;
        #pragma unroll
        for (int k = 0; k < KCH; ++k) {
            const int p0 = 4 * t + 4096 * k;
            const float4* v = (const float4*)(xb + (size_t)p0 * 3);
            float4 f0 = v[0], f1 = v[1], f2 = v[2];
            // point p0+0: (f0.x, f0.y, f0.z)
            // point p0+1: (f0.w, f1.x, f1.y)
            // point p0+2: (f1.z, f1.w, f2.x)
            // point p0+3: (f2.y, f2.z, f2.w)
            float px[4] = { f0.x, f0.w, f1.z, f2.y };
            float py[4] = { f0.y, f1.x, f1.w, f2.z };
            float pz[4] = { f0.z, f1.y, f2.x, f2.w };
            #pragma unroll
            for (int j = 0; j < 4; ++j) {
                // f64 mirror of np: d2 = (dx*dx + dy*dy) + dz*dz, no FMA
                double dx = (double)px[j] - cx;
                double dy = (double)py[j] - cy;
                double dz = (double)pz[j] - cz;
                double d2 = (dx*dx + dy*dy) + dz*dz;
                double od = dist[4*k+j];
                double nd = (d2 < od) ? d2 : od;    // np.minimum (no NaNs here)
                dist[4*k+j] = nd;
                int pidx = p0 + j;
                // per-thread indices visited in ascending order -> strict >
                // keeps the first (lowest-index) maximum, like np.argmax
                bool took = nd > best;
                best    = took ? nd   : best;
                bestIdx = took ? pidx : bestIdx;
            }
        }
        // wave-level argmax, first-index tie-break
        #pragma unroll
        for (int off = 32; off >= 1; off >>= 1) {
            double ov = __shfl_xor(best, off);
            int    oi = __shfl_xor(bestIdx, off);
            if (ov > best || (ov == best && oi < bestIdx)) { best = ov; bestIdx = oi; }
        }
        const int buf = it & 1;
        if (lane == 0) { red_v[buf][wave] = best; red_i[buf][wave] = bestIdx; }
        __syncthreads();
        // all threads redundantly scan the 16 wave results (uniform result);
        // double-buffered slots make next iteration's writes safe with a
        // single barrier per iteration.
        double wv = red_v[buf][0];
        int    wi = red_i[buf][0];
        #pragma unroll
        for (int w = 1; w < NWAVES; ++w) {
            double v2 = red_v[buf][w];
            int    i2 = red_i[buf][w];
            if (v2 > wv || (v2 == wv && i2 < wi)) { wv = v2; wi = i2; }
        }
        if (t == 0 && it + 1 < NPOINT) fps_out[b * NPOINT + it + 1] = wi;
        // broadcast load of next centroid (uniform address, L2-hot)
        cx = (double)xb[wi * 3 + 0];
        cy = (double)xb[wi * 3 + 1];
        cz = (double)xb[wi * 3 + 2];
    }
}

// Gather + transpose: out = [new_xyz (B,3,S) | new_features (B,C,S)], S=2048, C=128
__global__ void gather_kernel(const float* __restrict__ xyz,
                              const float* __restrict__ feat,
                              const int*   __restrict__ fps_idx,
                              float*       __restrict__ out)
{
    const int blk = blockIdx.x;
    const int s = blk & (NPOINT - 1);
    const int b = blk >> 11;
    const int idx = fps_idx[b * NPOINT + s];
    const int c = threadIdx.x;  // 128 threads
    const float v = feat[((size_t)(b * NPT + idx)) * 128 + c];
    out[(size_t)BATCH * 3 * NPOINT + ((size_t)(b * 128 + c)) * NPOINT + s] = v;
    if (c < 3) {
        out[((size_t)(b * 3 + c)) * NPOINT + s] =
            xyz[((size_t)(b * NPT + idx)) * 3 + c];
    }
}

extern "C" void kernel_launch(void* const* d_in, const int* in_sizes, int n_in,
                              void* d_out, int out_size, void* d_ws, size_t ws_size,
                              hipStream_t stream) {
    const float* xyz      = (const float*)d_in[0];  // [16, 32768, 3]
    const float* features = (const float*)d_in[1];  // [16, 32768, 128]
    const int*   init_far = (const int*)d_in[2];    // [16]
    float* out = (float*)d_out;
    int*   fps_idx = (int*)d_ws;                    // 128 KiB in workspace

    fps_kernel<<<BATCH, TPB, 0, stream>>>(xyz, init_far, fps_idx);
    gather_kernel<<<BATCH * NPOINT, 128, 0, stream>>>(xyz, features, fps_idx, out);
}